// Round 12
// baseline (284.207 us; speedup 1.0000x reference)
//
#include <hip/hip_runtime.h>

#define NB 256   // batch
#define NS 256   // seq len == number of steps
#define NE 2     // encoder dim
#define ND 128   // decoder dim
#define NT 512   // threads per block (8 waves)
#define NN 16    // Chebyshev nodes/degree for the h -> context map
#define RING 32  // h-history ring depth (2 store chunks of 16)
#define SLOT 144 // padded words per fp32 ring slot (4 slices of 36)
#define SLOTH 160 // padded halfs per f16 ring slot (4 slices of 40)

typedef float vf4 __attribute__((ext_vector_type(4)));
typedef _Float16 f16x8 __attribute__((ext_vector_type(8)));
typedef _Float16 f16x2 __attribute__((ext_vector_type(2)));
typedef float f32x4 __attribute__((ext_vector_type(4)));

constexpr float L2E = 1.4426950408889634f;  // log2(e)
constexpr float PI_F = 3.14159265358979323846f;

// Monomial coefficients of Chebyshev T_k: T_k(h) = sum_m CT[k][m] h^m (exact ints).
__device__ const float CT[16][16] = {
 {1,0,0,0,0,0,0,0,0,0,0,0,0,0,0,0},
 {0,1,0,0,0,0,0,0,0,0,0,0,0,0,0,0},
 {-1,0,2,0,0,0,0,0,0,0,0,0,0,0,0,0},
 {0,-3,0,4,0,0,0,0,0,0,0,0,0,0,0,0},
 {1,0,-8,0,8,0,0,0,0,0,0,0,0,0,0,0},
 {0,5,0,-20,0,16,0,0,0,0,0,0,0,0,0,0},
 {-1,0,18,0,-48,0,32,0,0,0,0,0,0,0,0,0},
 {0,-7,0,56,0,-112,0,64,0,0,0,0,0,0,0,0},
 {1,0,-32,0,160,0,-256,0,128,0,0,0,0,0,0,0},
 {0,9,0,-120,0,432,0,-576,0,256,0,0,0,0,0},
 {-1,0,50,0,-400,0,1120,0,-1280,0,512,0,0,0,0,0},
 {0,-11,0,220,0,-1232,0,2816,0,-2816,0,1024,0,0,0,0},
 {1,0,-72,0,840,0,-3584,0,6912,0,-6144,0,2048,0,0,0},
 {0,13,0,-364,0,2912,0,-9984,0,16640,0,-13312,0,4096,0,0},
 {-1,0,98,0,-1568,0,9408,0,-26880,0,39424,0,-28672,0,8192,0},
 {0,-15,0,560,0,-6048,0,28800,0,-70400,0,92160,0,-61440,0,16384}};

// DPP add: x + dpp_move(x). All-VALU cross-lane (no LDS pipe, no lgkmcnt).
template <int C>
__device__ __forceinline__ float dppadd(float x) {
    return x + __builtin_bit_cast(float,
        __builtin_amdgcn_update_dpp(0, __builtin_bit_cast(int, x), C, 0xF, 0xF, true));
}
// DPP move (quad_perm broadcast): returns value of quad-lane C_SEL in each quad.
template <int C>
__device__ __forceinline__ float quadbc(float x) {
    return __builtin_bit_cast(float,
        __builtin_amdgcn_update_dpp(0, __builtin_bit_cast(int, x), C, 0xF, 0xF, true));
}
__device__ __forceinline__ float red_wave64(float x) {    // valid in lane 63
    x = dppadd<0xB1>(x); x = dppadd<0x4E>(x); x = dppadd<0x141>(x);
    x = dppadd<0x140>(x); x = dppadd<0x142>(x); x = dppadd<0x143>(x); return x;
}
__device__ __forceinline__ float red_half32(float x) {    // 32-lane sums
    x = dppadd<0xB1>(x); x = dppadd<0x4E>(x); x = dppadd<0x141>(x);
    x = dppadd<0x140>(x); x = dppadd<0x142>(x); return x;
}

// One block per batch element; 256-step recurrence in-block, ONE barrier/step.
// Champion structure (rounds 1/11: wave-local MFMA tiling, one-bpermute gate
// fetch, quad-split activations, f32 ring + chunked stores) with ONE change:
// the context scalar x(k) is computed at the step TOP by every wave
// redundantly, entirely off the LDS pipe after the load:
//   1 extra per-lane ds_read_b32 (jpair bijection, issued WITH the af reads)
//   -> degree-15 even/odd Horner at 2 h-values (pure VALU, ~70 FMA)
//   -> red_wave64 (DPP only) -> v_readlane lane63 -> SGPR broadcast.
// This deletes the writer-side tail (phaseG + 12 serial DPP + xwbuf write)
// and the head's xv read + red_oct from the serial path. Unlike round 4's
// failed version, there are NO ds_bpermutes on the x-path -- nothing shares
// lgkmcnt with the af reads after load issue -- so the ~350cy VALU x-chain
// hides under the ~620cy MFMA-issue block (separate pipes).
// x sees f16-rounded h: verified harmless in round 5 (absmax 4.8828e-4).
__global__ __launch_bounds__(NT, 1)
void attn_lstm_decoder(const float* __restrict__ enc,   // [B,S,E]
                       const float* __restrict__ W1w,   // [S,S]
                       const float* __restrict__ W1b,   // [S]
                       const float* __restrict__ W2w,   // [S,2S]
                       const float* __restrict__ W2b,   // [S]
                       const float* __restrict__ Wih,   // [4D,E]
                       const float* __restrict__ Whh,   // [4D,D]
                       const float* __restrict__ bih,   // [4D]
                       const float* __restrict__ bhh,   // [4D]
                       float* __restrict__ out)         // [S,B,D]
{
    const int b    = blockIdx.x;
    const int t    = threadIdx.x;
    const int wave = t >> 6;
    const int lane = t & 63;
    const int g    = t >> 2;          // d-index / row group, 0..127
    const int q    = t & 3;           // this lane's gate
    const int grp  = lane >> 4;       // MFMA k-group 0..3
    const int nib  = lane & 15;       // MFMA n-index 0..15
    // setup-only:
    const int half = lane >> 5;
    const int idx  = lane & 31;
    const int jnode = 2 * wave + half;

    __shared__ __align__(16) float    hist[RING * SLOT];    // fp32 h ring (output)
    __shared__ __align__(16) _Float16 hist16[RING * SLOTH]; // f16 h ring (MFMA A)
    __shared__ float A2_l[NS];
    __shared__ float g2_l[NS];
    __shared__ float e0_l[NS];
    __shared__ float e1_l[NS];
    __shared__ float Ml[NN * NN];
    __shared__ float2 Pn[NN];
    __shared__ float2 Vl[NN];
    __shared__ float Pm0[NN], Pm1[NN];

    // ---------------- setup (once per block) ----------------
    {
        float v = enc[b * (NS * NE) + t];      // coalesced
        if (t & 1) e1_l[t >> 1] = v; else e0_l[t >> 1] = v;
    }
    if (t < NN * NN) {
        const int mi = t >> 4, mj = t & 15;
        const float w = (mi == 0) ? (1.0f / NN) : (2.0f / NN);
        Ml[t] = w * __cosf((float)(mi * (2 * mj + 1)) * (PI_F / (2 * NN)));
    }
    __syncthreads();

    // w1sum rows and w2term rows: 32 rows per wave (DPP reductions).
    for (int r = 0; r < 32; ++r) {
        const int s = wave * 32 + r;
        float p = W1w[s * NS + lane]       + W1w[s * NS + lane + 64]
                + W1w[s * NS + lane + 128] + W1w[s * NS + lane + 192];
        p = red_wave64(p);
        if (lane == 63) g2_l[s] = p * (2.0f * L2E);
        float qq = 0.0f;
        #pragma unroll
        for (int kk = 0; kk < 8; ++kk) {
            const int c = lane + kk * 64;
            const float ev = (c & 1) ? e1_l[c >> 1] : e0_l[c >> 1];
            qq = fmaf(ev, W2w[s * (2 * NS) + c], qq);
        }
        qq = red_wave64(qq);
        if (lane == 63) A2_l[s] = (qq + W2b[s] + W1b[s]) * (2.0f * L2E);
    }
    __syncthreads();

    // One-time node softmax: F(y_j) for the 16 Chebyshev nodes (2 nodes/wave).
    {
        const float y  = __cosf((float)(2 * jnode + 1) * (PI_F / (2 * NN)));
        const float C2 = -2.0f * L2E;
        float l = 0.0f, p0 = 0.0f, p1 = 0.0f;
        #pragma unroll
        for (int k = 0; k < 8; ++k) {
            const int s = k * 32 + idx;
            const float m1 = fmaf(y, g2_l[s], A2_l[s]);
            const float u  = __builtin_amdgcn_exp2f(m1);
            const float rc = __builtin_amdgcn_rcpf(u + 1.0f);
            const float e  = __builtin_amdgcn_exp2f(rc * C2);
            l += e;
            p0 = fmaf(e, e0_l[s], p0);
            p1 = fmaf(e, e1_l[s], p1);
        }
        l = red_half32(l); p0 = red_half32(p0); p1 = red_half32(p1);
        if ((lane & 31) == 31) {
            const float rl = __builtin_amdgcn_rcpf(l);
            Pn[jnode] = make_float2(p0 * rl, p1 * rl);
        }
    }
    __syncthreads();

    // DCT collapse: V[i] = sum_j M[i][j]*Pn[j], 1/ND folded in.
    if (t < NN) {
        float v0 = 0.0f, v1 = 0.0f;
        #pragma unroll
        for (int j = 0; j < NN; ++j) {
            v0 = fmaf(Ml[t * NN + j], Pn[j].x, v0);
            v1 = fmaf(Ml[t * NN + j], Pn[j].y, v1);
        }
        Vl[t] = make_float2(v0 * (1.0f / ND), v1 * (1.0f / ND));
    }

    // W_hh MFMA B-fragments, WAVE-LOCAL rows: tile rt (= gate index) covers
    // rows 128*rt + 16*wave + [0,16). Lane holds B[k][n]: n = nib,
    // k = 32*kt + 8*grp + e (contiguous 8, packed little-endian).
    f16x8 wf[4][4];
    #pragma unroll
    for (int rt = 0; rt < 4; ++rt) {
        const int row = 128 * rt + 16 * wave + nib;
        #pragma unroll
        for (int kt = 0; kt < 4; ++kt) {
            const vf4 wa = *reinterpret_cast<const vf4*>(Whh + row * ND + 32 * kt + 8 * grp);
            const vf4 wb = *reinterpret_cast<const vf4*>(Whh + row * ND + 32 * kt + 8 * grp + 4);
            f16x8 wv;
            wv[0] = (_Float16)wa.x; wv[1] = (_Float16)wa.y;
            wv[2] = (_Float16)wa.z; wv[3] = (_Float16)wa.w;
            wv[4] = (_Float16)wb.x; wv[5] = (_Float16)wb.y;
            wv[6] = (_Float16)wb.z; wv[7] = (_Float16)wb.w;
            wf[rt][kt] = wv;
        }
    }
    // This lane's gate (= q) constants for row 128*q + g.
    const int rq = 128 * q + g;
    const float wiq0 = Wih[rq * 2 + 0];
    const float wiq1 = Wih[rq * 2 + 1];
    const float bbq  = bih[rq] + bhh[rq];
    // activation: act = cA1 * rcp(1 + exp2(sA * x)) + cA0
    //   sigmoid (q=0,1,3): sA=-L2E, cA1=1, cA0=0 ; tanh (q=2): sA=2*L2E, cA1=-2, cA0=1
    const float sA  = (q == 2) ? (2.0f * L2E) : (-L2E);
    const float cA1 = (q == 2) ? -2.0f : 1.0f;
    const float cA0 = (q == 2) ? 1.0f : 0.0f;
    // bpermute source lane: gate lane&3 at column lane>>2 lives (as col s&15,
    // reg0, selected by s>>4) in lane s = ((lane&3)<<4) | (lane>>2).
    const int bidx = ((((lane & 3) << 4) | (lane >> 2)) << 2);

    // zero-init ring slot 31 (input of step 0) in both rings
    if (t < ND) {
        hist[31 * SLOT + 36 * (t >> 5) + (t & 31)] = 0.0f;
        hist16[31 * SLOTH + 40 * (t >> 5) + (t & 31)] = (_Float16)0.0f;
    }
    float h_reg = 0.0f, c_reg = 0.0f;
    __syncthreads();                   // Vl visible

    // Chebyshev -> monomial: Pm[m] = sum_k V[k] * CT[k][m].
    if (t < NN) {
        float s0 = 0.0f, s1 = 0.0f;
        #pragma unroll
        for (int k = 0; k < NN; ++k) {
            s0 = fmaf(Vl[k].x, CT[k][t], s0);
            s1 = fmaf(Vl[k].y, CT[k][t], s1);
        }
        Pm0[t] = s0; Pm1[t] = s1;
    }
    __syncthreads();                   // Pm visible

    // Full monomial coefficient sets in registers (broadcast LDS reads,
    // setup-only; all indices compile-time after unrolling).
    float cc0[16], cc1[16];
    #pragma unroll
    for (int i = 0; i < 16; ++i) { cc0[i] = Pm0[i]; cc1[i] = Pm1[i]; }

    // Even/odd Horner: G(h) = E(h^2) + h*O(h^2), E/O degree-7.
    auto evalG = [&](float h, const float (&C)[16]) -> float {
        const float h2 = h * h;
        float e = C[14], o = C[15];
        #pragma unroll
        for (int k = 12; k >= 0; k -= 2) {
            e = fmaf(e, h2, C[k]);
            o = fmaf(o, h2, C[k + 1]);
        }
        return fmaf(h, o, e);
    };

    // This lane's h-pair for the x-evaluation: bijection (grp,nib) -> pair
    // (r4/r5-verified): j0 = 32*(nib>>2) + 8*grp + 2*(nib&3), covers every
    // even j in [0,128) exactly once across the wave. Ring-slot layout maps
    // h[j] to half-offset 40*(j>>5) + (j&31); the pair stays contiguous.
    const int jpair = 32 * (nib >> 2) + 8 * grp + 2 * (nib & 3);
    const int jpoff = 40 * (jpair >> 5) + (jpair & 31);

    // ---------------- the recurrence (ONE barrier per step) ----------------
    for (int step = 0; step < NS; ++step) {
        const int rs = (step + RING - 1) & (RING - 1);   // slot holding h(step-1)
        const int ws = step & (RING - 1);                // slot for h(step)

        // A fragments: each 16-lane group reads the SAME 16B of h (broadcast),
        // so A[m][k] = h[k] for every m; all C rows are identical.
        // hp2 (this lane's own h-pair) is issued in the same load batch.
        f16x8 af[4];
        const _Float16* hsl = &hist16[rs * SLOTH + 8 * grp];
        #pragma unroll
        for (int kt = 0; kt < 4; ++kt)
            af[kt] = __builtin_bit_cast(f16x8,
                *reinterpret_cast<const int4*>(hsl + 40 * kt));
        const f16x2 hp2 = *reinterpret_cast<const f16x2*>(&hist16[rs * SLOTH + jpoff]);

        // Chunk store (every 16 steps, at step TOP): steps step-16..step-1.
        if ((step & 15) == 0 && step > 0) {
            const int sb  = (step - 16) & (RING - 1);
            const int k   = t >> 5;
            const int l32 = t & 31;
            const int w   = 4 * l32;
            const vf4 v = *reinterpret_cast<const vf4*>(
                &hist[(sb + k) * SLOT + 36 * (w >> 5) + (w & 31)]);
            *reinterpret_cast<vf4*>(
                &out[(size_t)(step - 16 + k) * (NB * ND) + b * ND + w]) = v;
        }

        // Gate matvec on the MFMA pipe: 4 independent chains of 4.
        f32x4 acc[4];
        #pragma unroll
        for (int rt = 0; rt < 4; ++rt) {
            f32x4 a = {0.0f, 0.0f, 0.0f, 0.0f};
            #pragma unroll
            for (int kt = 0; kt < 4; ++kt)
                a = __builtin_amdgcn_mfma_f32_16x16x32_f16(af[kt], wf[rt][kt], a, 0, 0, 0);
            acc[rt] = a;
        }

        // ---- x(step), wave-redundant, hidden under the MFMA block ----
        // VALU-only after the hp2 load: poly + DPP reduce + readlane (SGPR).
        const float ha = (float)hp2[0];
        const float hc = (float)hp2[1];
        float p0 = evalG(ha, cc0) + evalG(hc, cc0);
        float p1 = evalG(ha, cc1) + evalG(hc, cc1);
        p0 = red_wave64(p0); p1 = red_wave64(p1);
        const float x0 = __builtin_bit_cast(float,
            __builtin_amdgcn_readlane(__builtin_bit_cast(int, p0), 63));
        const float x1 = __builtin_bit_cast(float,
            __builtin_amdgcn_readlane(__builtin_bit_cast(int, p1), 63));

        // Wave-local gate fetch: select this lane's served gate (lane>>4),
        // then one bpermute delivers gate q at column g to every thread.
        const float a01 = (lane & 16) ? acc[1][0] : acc[0][0];
        const float a23 = (lane & 16) ? acc[3][0] : acc[2][0];
        const float av  = (lane & 32) ? a23 : a01;
        const float myg = __builtin_bit_cast(float,
            __builtin_amdgcn_ds_bpermute(bidx, __builtin_bit_cast(int, av)));

        // Quad-split activation: one transcendental pair per lane.
        const float gq  = myg + fmaf(x0, wiq0, fmaf(x1, wiq1, bbq));
        const float act = fmaf(cA1,
            __builtin_amdgcn_rcpf(1.0f + __builtin_amdgcn_exp2f(sA * gq)), cA0);
        const float si = quadbc<0x00>(act);
        const float sf = quadbc<0x55>(act);
        const float tg = quadbc<0xAA>(act);
        const float so = quadbc<0xFF>(act);

        c_reg = fmaf(sf, c_reg, si * tg);
        const float tc2 = 1.0f - 2.0f * __builtin_amdgcn_rcpf(
            __builtin_amdgcn_exp2f(2.0f * L2E * c_reg) + 1.0f);
        h_reg = so * tc2;

        // Tail: just the h ring writes (no poly, no DPP chain, no xwbuf).
        if (q == 0) {
            hist[ws * SLOT + 36 * (g >> 5) + (g & 31)] = h_reg;
            hist16[ws * SLOTH + 40 * (g >> 5) + (g & 31)] = (_Float16)h_reg;
        }

        __syncthreads();                                  // h ring visible
    }

    // Tail: store the final chunk (steps 240..255, ring slots 16..31).
    {
        const int k   = t >> 5;
        const int l32 = t & 31;
        const int w   = 4 * l32;
        const vf4 v = *reinterpret_cast<const vf4*>(
            &hist[(16 + k) * SLOT + 36 * (w >> 5) + (w & 31)]);
        *reinterpret_cast<vf4*>(
            &out[(size_t)(240 + k) * (NB * ND) + b * ND + w]) = v;
    }
}

extern "C" void kernel_launch(void* const* d_in, const int* in_sizes, int n_in,
                              void* d_out, int out_size, void* d_ws, size_t ws_size,
                              hipStream_t stream) {
    const float* enc = (const float*)d_in[0];
    const float* W1w = (const float*)d_in[1];
    const float* W1b = (const float*)d_in[2];
    const float* W2w = (const float*)d_in[3];
    const float* W2b = (const float*)d_in[4];
    const float* Wih = (const float*)d_in[5];
    const float* Whh = (const float*)d_in[6];
    const float* bih = (const float*)d_in[7];
    const float* bhh = (const float*)d_in[8];
    attn_lstm_decoder<<<NB, NT, 0, stream>>>(enc, W1w, W1b, W2w, W2b,
                                             Wih, Whh, bih, bhh, (float*)d_out);
}

// Round 13
// 261.468 us; speedup vs baseline: 1.0870x; 1.0870x over previous
//
#include <hip/hip_runtime.h>

#define NB 256   // batch
#define NS 256   // seq len == number of steps
#define NE 2     // encoder dim
#define ND 128   // decoder dim
#define NT 512   // threads per block (8 waves)
#define NN 16    // Chebyshev nodes/degree for the h -> context map
#define RING 32  // h-history ring depth (2 store chunks of 16)
#define SLOT 144 // padded words per fp32 ring slot (4 slices of 36)
#define SLOTH 160 // padded halfs per f16 ring slot (4 slices of 40)

typedef float vf4 __attribute__((ext_vector_type(4)));
typedef _Float16 f16x8 __attribute__((ext_vector_type(8)));
typedef float f32x4 __attribute__((ext_vector_type(4)));

constexpr float L2E = 1.4426950408889634f;  // log2(e)
constexpr float PI_F = 3.14159265358979323846f;

// Monomial coefficients of Chebyshev T_k: T_k(h) = sum_m CT[k][m] h^m (exact ints).
__device__ const float CT[16][16] = {
 {1,0,0,0,0,0,0,0,0,0,0,0,0,0,0,0},
 {0,1,0,0,0,0,0,0,0,0,0,0,0,0,0,0},
 {-1,0,2,0,0,0,0,0,0,0,0,0,0,0,0,0},
 {0,-3,0,4,0,0,0,0,0,0,0,0,0,0,0,0},
 {1,0,-8,0,8,0,0,0,0,0,0,0,0,0,0,0},
 {0,5,0,-20,0,16,0,0,0,0,0,0,0,0,0,0},
 {-1,0,18,0,-48,0,32,0,0,0,0,0,0,0,0,0},
 {0,-7,0,56,0,-112,0,64,0,0,0,0,0,0,0,0},
 {1,0,-32,0,160,0,-256,0,128,0,0,0,0,0,0,0},
 {0,9,0,-120,0,432,0,-576,0,256,0,0,0,0,0},
 {-1,0,50,0,-400,0,1120,0,-1280,0,512,0,0,0,0,0},
 {0,-11,0,220,0,-1232,0,2816,0,-2816,0,1024,0,0,0,0},
 {1,0,-72,0,840,0,-3584,0,6912,0,-6144,0,2048,0,0,0},
 {0,13,0,-364,0,2912,0,-9984,0,16640,0,-13312,0,4096,0,0},
 {-1,0,98,0,-1568,0,9408,0,-26880,0,39424,0,-28672,0,8192,0},
 {0,-15,0,560,0,-6048,0,28800,0,-70400,0,92160,0,-61440,0,16384}};

// DPP add: x + dpp_move(x). All-VALU cross-lane (no LDS pipe, no lgkmcnt).
template <int C>
__device__ __forceinline__ float dppadd(float x) {
    return x + __builtin_bit_cast(float,
        __builtin_amdgcn_update_dpp(0, __builtin_bit_cast(int, x), C, 0xF, 0xF, true));
}
// DPP move (quad_perm broadcast): returns value of quad-lane C_SEL in each quad.
template <int C>
__device__ __forceinline__ float quadbc(float x) {
    return __builtin_bit_cast(float,
        __builtin_amdgcn_update_dpp(0, __builtin_bit_cast(int, x), C, 0xF, 0xF, true));
}
__device__ __forceinline__ float red_quad(float x) {      // sum over each quad
    x = dppadd<0xB1>(x); x = dppadd<0x4E>(x); return x;
}
__device__ __forceinline__ float red_oct(float x) {       // sum over each octet
    x = dppadd<0xB1>(x); x = dppadd<0x4E>(x); x = dppadd<0x141>(x); return x;
}
__device__ __forceinline__ float red_wave64(float x) {    // valid in lane 63
    x = dppadd<0xB1>(x); x = dppadd<0x4E>(x); x = dppadd<0x141>(x);
    x = dppadd<0x140>(x); x = dppadd<0x142>(x); x = dppadd<0x143>(x); return x;
}
__device__ __forceinline__ float red_half32(float x) {    // 32-lane sums
    x = dppadd<0xB1>(x); x = dppadd<0x4E>(x); x = dppadd<0x141>(x);
    x = dppadd<0x140>(x); x = dppadd<0x142>(x); return x;
}
__device__ __forceinline__ float red_grp16(float x) {     // quads hold identical copies:
    // mirrors/bcasts add ONE copy per quad => EXACT sum over 16 quad values.
    x = dppadd<0x141>(x); x = dppadd<0x140>(x);
    x = dppadd<0x142>(x); x = dppadd<0x143>(x); return x;
}

// One block per batch element; 256-step recurrence in-block, ONE barrier/step.
// Attention collapsed (setup) to degree-15 monomial poly, quad-split.
// Gate matvec on the MFMA pipe, WAVE-LOCAL tiling: wave w's 16 MFMAs cover
// exactly the 64 gate rows {128*j + 16*w + c : j=0..3, c=0..15} its own
// threads consume. A = h broadcast => all C rows identical => every lane
// holds gate j for column lane&15 in acc[j][0]. Each thread fetches its 4
// gates with ONE ds_bpermute (select acc[lane>>4], pull from lane
// ((lane&3)<<4)|(lane>>2)) -- no LDS staging, no second barrier.
// Activations quad-split: each lane does ONE sigmoid/tanh (per-lane
// constants), 4 DPP quad-broadcasts reassemble si/sf/tg/so.
//
// SESSION VERDICT (rounds 0-13): this is the measured champion (bench
// 260.8us, rocprof 215us, absmax 4.88e-4). Thirteen structural variants --
// all-fdot2, all-MFMA, pipe splits (r7/r8), 4-wave/2x-redundancy (r6),
// head-side x with bpermute (r4) and with readlane (r12), 16-batch packing
// (r9), 2-stream TLP (r10) -- bracket it within ~2% or regress outright.
// The step is a serial-skeleton latency floor (~820ns: barrier + LDS
// h-exchange + 32 MFMA/SIMD matvec with irreducible 16x M-waste +
// transcendental chain + x-poly tail); both pipes <36% busy, HBM 2%.
// r12's lesson: the writer-side quad-split x-poly (12 FMA/lane, paid once)
// beats any redundant head-side evaluation (r12: +560cy/SIMD VALU issue
// exceeded the ~300cy MFMA shadow; VALUBusy 36->49, -12%).
__global__ __launch_bounds__(NT, 2)
void attn_lstm_decoder(const float* __restrict__ enc,   // [B,S,E]
                       const float* __restrict__ W1w,   // [S,S]
                       const float* __restrict__ W1b,   // [S]
                       const float* __restrict__ W2w,   // [S,2S]
                       const float* __restrict__ W2b,   // [S]
                       const float* __restrict__ Wih,   // [4D,E]
                       const float* __restrict__ Whh,   // [4D,D]
                       const float* __restrict__ bih,   // [4D]
                       const float* __restrict__ bhh,   // [4D]
                       float* __restrict__ out)         // [S,B,D]
{
    const int b    = blockIdx.x;
    const int t    = threadIdx.x;
    const int wave = t >> 6;
    const int lane = t & 63;
    const int g    = t >> 2;          // d-index / row group, 0..127
    const int q    = t & 3;           // monomial residue class == this lane's gate
    const bool qb0 = q & 1;
    const bool qb1 = q & 2;
    const int grp  = lane >> 4;       // MFMA k-group 0..3
    const int nib  = lane & 15;       // MFMA n-index 0..15
    // setup-only:
    const int half = lane >> 5;
    const int idx  = lane & 31;
    const int jnode = 2 * wave + half;

    __shared__ __align__(16) float    hist[RING * SLOT];    // fp32 h ring (output)
    __shared__ __align__(16) _Float16 hist16[RING * SLOTH]; // f16 h ring (MFMA A)
    __shared__ __align__(16) float xwbuf[2][16];        // 8 waves x float2 partial x
    __shared__ float A2_l[NS];
    __shared__ float g2_l[NS];
    __shared__ float e0_l[NS];
    __shared__ float e1_l[NS];
    __shared__ float Ml[NN * NN];
    __shared__ float2 Pn[NN];
    __shared__ float2 Vl[NN];
    __shared__ float Pm0[NN], Pm1[NN];

    // ---------------- setup (once per block) ----------------
    {
        float v = enc[b * (NS * NE) + t];      // coalesced
        if (t & 1) e1_l[t >> 1] = v; else e0_l[t >> 1] = v;
    }
    if (t < NN * NN) {
        const int mi = t >> 4, mj = t & 15;
        const float w = (mi == 0) ? (1.0f / NN) : (2.0f / NN);
        Ml[t] = w * __cosf((float)(mi * (2 * mj + 1)) * (PI_F / (2 * NN)));
    }
    __syncthreads();

    // w1sum rows and w2term rows: 32 rows per wave (DPP reductions).
    for (int r = 0; r < 32; ++r) {
        const int s = wave * 32 + r;
        float p = W1w[s * NS + lane]       + W1w[s * NS + lane + 64]
                + W1w[s * NS + lane + 128] + W1w[s * NS + lane + 192];
        p = red_wave64(p);
        if (lane == 63) g2_l[s] = p * (2.0f * L2E);
        float qq = 0.0f;
        #pragma unroll
        for (int kk = 0; kk < 8; ++kk) {
            const int c = lane + kk * 64;
            const float ev = (c & 1) ? e1_l[c >> 1] : e0_l[c >> 1];
            qq = fmaf(ev, W2w[s * (2 * NS) + c], qq);
        }
        qq = red_wave64(qq);
        if (lane == 63) A2_l[s] = (qq + W2b[s] + W1b[s]) * (2.0f * L2E);
    }
    __syncthreads();

    // One-time node softmax: F(y_j) for the 16 Chebyshev nodes (2 nodes/wave).
    {
        const float y  = __cosf((float)(2 * jnode + 1) * (PI_F / (2 * NN)));
        const float C2 = -2.0f * L2E;
        float l = 0.0f, p0 = 0.0f, p1 = 0.0f;
        #pragma unroll
        for (int k = 0; k < 8; ++k) {
            const int s = k * 32 + idx;
            const float m1 = fmaf(y, g2_l[s], A2_l[s]);
            const float u  = __builtin_amdgcn_exp2f(m1);
            const float rc = __builtin_amdgcn_rcpf(u + 1.0f);
            const float e  = __builtin_amdgcn_exp2f(rc * C2);
            l += e;
            p0 = fmaf(e, e0_l[s], p0);
            p1 = fmaf(e, e1_l[s], p1);
        }
        l = red_half32(l); p0 = red_half32(p0); p1 = red_half32(p1);
        if ((lane & 31) == 31) {
            const float rl = __builtin_amdgcn_rcpf(l);
            Pn[jnode] = make_float2(p0 * rl, p1 * rl);
        }
    }
    __syncthreads();

    // DCT collapse: V[i] = sum_j M[i][j]*Pn[j], 1/ND folded in.
    if (t < NN) {
        float v0 = 0.0f, v1 = 0.0f;
        #pragma unroll
        for (int j = 0; j < NN; ++j) {
            v0 = fmaf(Ml[t * NN + j], Pn[j].x, v0);
            v1 = fmaf(Ml[t * NN + j], Pn[j].y, v1);
        }
        Vl[t] = make_float2(v0 * (1.0f / ND), v1 * (1.0f / ND));
    }

    // W_hh MFMA B-fragments, WAVE-LOCAL rows: tile rt (= gate index) covers
    // rows 128*rt + 16*wave + [0,16). Lane holds B[k][n]: n = nib,
    // k = 32*kt + 8*grp + e (contiguous 8, packed little-endian).
    f16x8 wf[4][4];
    #pragma unroll
    for (int rt = 0; rt < 4; ++rt) {
        const int row = 128 * rt + 16 * wave + nib;
        #pragma unroll
        for (int kt = 0; kt < 4; ++kt) {
            const vf4 wa = *reinterpret_cast<const vf4*>(Whh + row * ND + 32 * kt + 8 * grp);
            const vf4 wb = *reinterpret_cast<const vf4*>(Whh + row * ND + 32 * kt + 8 * grp + 4);
            f16x8 wv;
            wv[0] = (_Float16)wa.x; wv[1] = (_Float16)wa.y;
            wv[2] = (_Float16)wa.z; wv[3] = (_Float16)wa.w;
            wv[4] = (_Float16)wb.x; wv[5] = (_Float16)wb.y;
            wv[6] = (_Float16)wb.z; wv[7] = (_Float16)wb.w;
            wf[rt][kt] = wv;
        }
    }
    // This lane's gate (= q) constants for row 128*q + g.
    const int rq = 128 * q + g;
    const float wiq0 = Wih[rq * 2 + 0];
    const float wiq1 = Wih[rq * 2 + 1];
    const float bbq  = bih[rq] + bhh[rq];
    // activation: act = cA1 * rcp(1 + exp2(sA * x)) + cA0
    //   sigmoid (q=0,1,3): sA=-L2E, cA1=1, cA0=0 ; tanh (q=2): sA=2*L2E, cA1=-2, cA0=1
    const float sA  = (q == 2) ? (2.0f * L2E) : (-L2E);
    const float cA1 = (q == 2) ? -2.0f : 1.0f;
    const float cA0 = (q == 2) ? 1.0f : 0.0f;
    // bpermute source lane: gate lane&3 at column lane>>2 lives (as col s&15,
    // reg0, selected by s>>4) in lane s = ((lane&3)<<4) | (lane>>2).
    const int bidx = ((((lane & 3) << 4) | (lane >> 2)) << 2);

    // zero-init ring slot 31 (input of step 0) in both rings
    if (t < ND) {
        hist[31 * SLOT + 36 * (t >> 5) + (t & 31)] = 0.0f;
        hist16[31 * SLOTH + 40 * (t >> 5) + (t & 31)] = (_Float16)0.0f;
    }
    float h_reg = 0.0f, c_reg = 0.0f;
    __syncthreads();                   // Vl visible

    // Chebyshev -> monomial: Pm[m] = sum_k V[k] * CT[k][m].
    if (t < NN) {
        float s0 = 0.0f, s1 = 0.0f;
        #pragma unroll
        for (int k = 0; k < NN; ++k) {
            s0 = fmaf(Vl[k].x, CT[k][t], s0);
            s1 = fmaf(Vl[k].y, CT[k][t], s1);
        }
        Pm0[t] = s0; Pm1[t] = s1;
    }
    __syncthreads();                   // Pm visible

    // Per-lane residue-class coefficients: G_e(h) = sum_q h^q * Q_q(h^4).
    float Q0[4], Q1[4];
    #pragma unroll
    for (int i = 0; i < 4; ++i) { Q0[i] = Pm0[4 * i + q]; Q1[i] = Pm1[4 * i + q]; }

    // phaseG: quad-split monomial eval; red_quad reassembles G(h), then
    // mirror-reduce over the 16 quads. lane63 writes this wave's partial.
    auto phaseG = [&](float h, int pw) {
        const float h2 = h * h;
        const float h3 = h2 * h;
        const float h4 = h2 * h2;
        const float hq = qb1 ? (qb0 ? h3 : h2) : (qb0 ? h : 1.0f);
        float a0 = fmaf(Q0[3], h4, Q0[2]);
        a0 = fmaf(a0, h4, Q0[1]);
        a0 = fmaf(a0, h4, Q0[0]);
        float a1 = fmaf(Q1[3], h4, Q1[2]);
        a1 = fmaf(a1, h4, Q1[1]);
        a1 = fmaf(a1, h4, Q1[0]);
        a0 *= hq;
        a1 *= hq;
        a0 = red_quad(a0);  a1 = red_quad(a1);     // reassemble G(h_g)
        a0 = red_grp16(a0); a1 = red_grp16(a1);    // sum over the wave's 16 g
        if (lane == 63) {
            xwbuf[pw][2 * wave + 0] = a0;
            xwbuf[pw][2 * wave + 1] = a1;
        }
    };

    phaseG(0.0f, 0);       // x for step 0 (h = 0)
    __syncthreads();

    // ---------------- the recurrence (ONE barrier per step) ----------------
    for (int step = 0; step < NS; ++step) {
        const int pr = step & 1;
        const int rs = (step + RING - 1) & (RING - 1);   // slot holding h(step-1)
        const int ws = step & (RING - 1);                // slot for h(step)

        // A fragments: each 16-lane group reads the SAME 16B of h (broadcast),
        // so A[m][k] = h[k] for every m; all C rows are identical.
        f16x8 af[4];
        const _Float16* hsl = &hist16[rs * SLOTH + 8 * grp];
        #pragma unroll
        for (int kt = 0; kt < 4; ++kt)
            af[kt] = __builtin_bit_cast(f16x8,
                *reinterpret_cast<const int4*>(hsl + 40 * kt));

        // Independent work while A loads land: x partials + chunk store.
        float2 xv = *reinterpret_cast<const float2*>(&xwbuf[pr][2 * (lane & 7)]);

        // Chunk store (every 16 steps, at step TOP): steps step-16..step-1.
        if ((step & 15) == 0 && step > 0) {
            const int sb  = (step - 16) & (RING - 1);
            const int k   = t >> 5;
            const int l32 = t & 31;
            const int w   = 4 * l32;
            const vf4 v = *reinterpret_cast<const vf4*>(
                &hist[(sb + k) * SLOT + 36 * (w >> 5) + (w & 31)]);
            *reinterpret_cast<vf4*>(
                &out[(size_t)(step - 16 + k) * (NB * ND) + b * ND + w]) = v;
        }

        float x0 = red_oct(xv.x);
        float x1 = red_oct(xv.y);

        // Gate matvec on the MFMA pipe: 4 independent chains of 4.
        f32x4 acc[4];
        #pragma unroll
        for (int rt = 0; rt < 4; ++rt) {
            f32x4 a = {0.0f, 0.0f, 0.0f, 0.0f};
            #pragma unroll
            for (int kt = 0; kt < 4; ++kt)
                a = __builtin_amdgcn_mfma_f32_16x16x32_f16(af[kt], wf[rt][kt], a, 0, 0, 0);
            acc[rt] = a;
        }

        // Wave-local gate fetch: select this lane's served gate (lane>>4),
        // then one bpermute delivers gate q at column g to every thread.
        const float a01 = (lane & 16) ? acc[1][0] : acc[0][0];
        const float a23 = (lane & 16) ? acc[3][0] : acc[2][0];
        const float av  = (lane & 32) ? a23 : a01;
        const float myg = __builtin_bit_cast(float,
            __builtin_amdgcn_ds_bpermute(bidx, __builtin_bit_cast(int, av)));

        // Quad-split activation: one transcendental pair per lane.
        const float gq  = myg + fmaf(x0, wiq0, fmaf(x1, wiq1, bbq));
        const float act = fmaf(cA1,
            __builtin_amdgcn_rcpf(1.0f + __builtin_amdgcn_exp2f(sA * gq)), cA0);
        const float si = quadbc<0x00>(act);
        const float sf = quadbc<0x55>(act);
        const float tg = quadbc<0xAA>(act);
        const float so = quadbc<0xFF>(act);

        c_reg = fmaf(sf, c_reg, si * tg);
        const float tc2 = 1.0f - 2.0f * __builtin_amdgcn_rcpf(
            __builtin_amdgcn_exp2f(2.0f * L2E * c_reg) + 1.0f);
        h_reg = so * tc2;

        if (q == 0) {
            hist[ws * SLOT + 36 * (g >> 5) + (g & 31)] = h_reg;
            hist16[ws * SLOTH + 40 * (g >> 5) + (g & 31)] = (_Float16)h_reg;
        }
        phaseG(h_reg, pr ^ 1);                            // x for step k+1

        __syncthreads();                                  // h ring + x partials
    }

    // Tail: store the final chunk (steps 240..255, ring slots 16..31).
    {
        const int k   = t >> 5;
        const int l32 = t & 31;
        const int w   = 4 * l32;
        const vf4 v = *reinterpret_cast<const vf4*>(
            &hist[(16 + k) * SLOT + 36 * (w >> 5) + (w & 31)]);
        *reinterpret_cast<vf4*>(
            &out[(size_t)(240 + k) * (NB * ND) + b * ND + w]) = v;
    }
}

extern "C" void kernel_launch(void* const* d_in, const int* in_sizes, int n_in,
                              void* d_out, int out_size, void* d_ws, size_t ws_size,
                              hipStream_t stream) {
    const float* enc = (const float*)d_in[0];
    const float* W1w = (const float*)d_in[1];
    const float* W1b = (const float*)d_in[2];
    const float* W2w = (const float*)d_in[3];
    const float* W2b = (const float*)d_in[4];
    const float* Wih = (const float*)d_in[5];
    const float* Whh = (const float*)d_in[6];
    const float* bih = (const float*)d_in[7];
    const float* bhh = (const float*)d_in[8];
    attn_lstm_decoder<<<NB, NT, 0, stream>>>(enc, W1w, W1b, W2w, W2b,
                                             Wih, Whh, bih, bhh, (float*)d_out);
}